// Round 5
// baseline (521.677 us; speedup 1.0000x reference)
//
#include <hip/hip_runtime.h>
#include <hip/hip_bf16.h>
#include <stdint.h>

typedef float  f32x4  __attribute__((ext_vector_type(4)));
typedef float  f32x16 __attribute__((ext_vector_type(16)));
typedef short  s16x8  __attribute__((ext_vector_type(8)));

#define D_MODEL 2048
#define NHEADS  16
#define DK      128
#define BATCH   2
#define SEQ     2048
#define MROWS   (BATCH*SEQ)   // 4096

__device__ __forceinline__ unsigned short f2bf(float f) {
  union { float f; unsigned int u; } v; v.f = f;
  unsigned int r = v.u + 0x7FFFu + ((v.u >> 16) & 1u);
  return (unsigned short)(r >> 16);
}

// compiler-cast pack (m240: scalar casts fuse to cvt_pk; don't hand-write asm)
__device__ __forceinline__ unsigned int packbf_c(float lo, float hi) {
  __hip_bfloat16 l = __float2bfloat16(lo);
  __hip_bfloat16 h = __float2bfloat16(hi);
  unsigned short lu, hu;
  __builtin_memcpy(&lu, &l, 2);
  __builtin_memcpy(&hu, &h, 2);
  return (unsigned int)lu | ((unsigned int)hu << 16);
}

__device__ __forceinline__ void async16(const void* g, void* l) {
  __builtin_amdgcn_global_load_lds(
      (const __attribute__((address_space(1))) unsigned int*)g,
      (__attribute__((address_space(3))) unsigned int*)l,
      16, 0, 0);
}

// ---------------- fp32 -> bf16 convert, q/k/v in one launch ----------------
__global__ __launch_bounds__(256) void f2b3_kernel(const float* __restrict__ q,
                                                   const float* __restrict__ k,
                                                   const float* __restrict__ v,
                                                   unsigned short* __restrict__ qb,
                                                   unsigned short* __restrict__ kb,
                                                   unsigned short* __restrict__ vb) {
  const float* s; unsigned short* d;
  switch (blockIdx.y) {
    case 0:  s = q; d = qb; break;
    case 1:  s = k; d = kb; break;
    default: s = v; d = vb; break;
  }
  int i = blockIdx.x * 256 + threadIdx.x;
  const float4* s4 = (const float4*)s;
  float4 a = s4[2*i];
  float4 b = s4[2*i+1];
  s16x8 o;
  o[0] = (short)f2bf(a.x); o[1] = (short)f2bf(a.y);
  o[2] = (short)f2bf(a.z); o[3] = (short)f2bf(a.w);
  o[4] = (short)f2bf(b.x); o[5] = (short)f2bf(b.y);
  o[6] = (short)f2bf(b.z); o[7] = (short)f2bf(b.w);
  *(s16x8*)(d + 8*(size_t)i) = o;
}

// ---------------- weight transpose + convert: Wt[n][k] = bf16(W[k][n]) ----------------
__global__ __launch_bounds__(256) void wtrans_kernel(const float* __restrict__ Wq,
                                                     const float* __restrict__ Wk,
                                                     const float* __restrict__ Wv,
                                                     const float* __restrict__ Wo,
                                                     unsigned short* __restrict__ WqT,
                                                     unsigned short* __restrict__ WkT,
                                                     unsigned short* __restrict__ WvT,
                                                     unsigned short* __restrict__ WoT) {
  const float* W; unsigned short* Wt;
  switch (blockIdx.z) {
    case 0:  W = Wq; Wt = WqT; break;
    case 1:  W = Wk; Wt = WkT; break;
    case 2:  W = Wv; Wt = WvT; break;
    default: W = Wo; Wt = WoT; break;
  }
  __shared__ float tl[32][33];
  int x = threadIdx.x, y = threadIdx.y;
  int n0 = blockIdx.x * 32, k0 = blockIdx.y * 32;
  #pragma unroll
  for (int j = 0; j < 32; j += 8)
    tl[y + j][x] = W[(size_t)(k0 + y + j) * D_MODEL + n0 + x];
  __syncthreads();
  #pragma unroll
  for (int j = 0; j < 32; j += 8)
    Wt[(size_t)(n0 + y + j) * D_MODEL + k0 + x] = f2bf(tl[x][y + j]);
}

// ---------------- GEMM, 2-phase counted-prefetch (T3-min): C = A Bt^T + bias ----------------
// LDS double-buffer; STAGE(t+1) issued before compute(t); one vmcnt(0)+barrier per K-step.
__global__ __launch_bounds__(256) void gemm_bt(const unsigned short* __restrict__ A,
                                               const unsigned short* __restrict__ Bt,
                                               const float* __restrict__ bias,
                                               void* __restrict__ Cout,
                                               int M, int N, int K,
                                               int mode, float scale) {
  __shared__ unsigned short As[2][128*32];
  __shared__ unsigned short Bs[2][128*32];
  const int t  = threadIdx.x;
  const int l  = t & 63, w = t >> 6;
  const int wr = w >> 1, wc = w & 1;
  const int m0 = blockIdx.y * 128, n0 = blockIdx.x * 128;
  const int lr = l & 15, lg = l >> 4;

  const int c0row = t >> 2, c0col = (t & 3) * 8;
  const int c1row = (t + 256) >> 2, c1col = ((t + 256) & 3) * 8;

  // prologue: stage k0=0 into buf 0
  async16(A  + (size_t)(m0 + c0row)*K + c0col, (char*)As[0] + t*16);
  async16(Bt + (size_t)(n0 + c0row)*K + c0col, (char*)Bs[0] + t*16);
  async16(A  + (size_t)(m0 + c1row)*K + c1col, (char*)As[0] + (t+256)*16);
  async16(Bt + (size_t)(n0 + c1row)*K + c1col, (char*)Bs[0] + (t+256)*16);
  asm volatile("s_waitcnt vmcnt(0)" ::: "memory");
  __syncthreads();

  f32x4 acc[4][4] = {};

  for (int k0 = 0; k0 < K; k0 += 32) {
    const int cur = (k0 >> 5) & 1;
    if (k0 + 32 < K) {
      const int kn = k0 + 32;
      async16(A  + (size_t)(m0 + c0row)*K + kn + c0col, (char*)As[cur^1] + t*16);
      async16(Bt + (size_t)(n0 + c0row)*K + kn + c0col, (char*)Bs[cur^1] + t*16);
      async16(A  + (size_t)(m0 + c1row)*K + kn + c1col, (char*)As[cur^1] + (t+256)*16);
      async16(Bt + (size_t)(n0 + c1row)*K + kn + c1col, (char*)Bs[cur^1] + (t+256)*16);
    }

    s16x8 af[4], bfr[4];
    #pragma unroll
    for (int m = 0; m < 4; ++m)
      af[m] = *(const s16x8*)&As[cur][(wr*64 + m*16 + lr)*32 + 8*lg];
    #pragma unroll
    for (int n = 0; n < 4; ++n)
      bfr[n] = *(const s16x8*)&Bs[cur][(wc*64 + n*16 + lr)*32 + 8*lg];
    #pragma unroll
    for (int m = 0; m < 4; ++m)
      #pragma unroll
      for (int n = 0; n < 4; ++n)
        acc[m][n] = __builtin_amdgcn_mfma_f32_16x16x32_bf16(af[m], bfr[n], acc[m][n], 0, 0, 0);

    asm volatile("s_waitcnt vmcnt(0)" ::: "memory");   // next-tile loads landed
    __syncthreads();
  }

  if (mode == 0) {
    float* C = (float*)Cout;
    #pragma unroll
    for (int n = 0; n < 4; ++n) {
      int col = n0 + wc*64 + n*16 + lr;
      float bv = bias[col];
      #pragma unroll
      for (int m = 0; m < 4; ++m) {
        int rowb = m0 + wr*64 + m*16 + lg*4;
        #pragma unroll
        for (int r = 0; r < 4; ++r)
          C[(size_t)(rowb + r)*N + col] = (acc[m][n][r] + bv) * scale;
      }
    }
  } else {
    unsigned short* C = (unsigned short*)Cout;
    #pragma unroll
    for (int n = 0; n < 4; ++n) {
      int col = n0 + wc*64 + n*16 + lr;
      float bv = bias[col];
      int h = col >> 7, dkk = col & 127;
      #pragma unroll
      for (int m = 0; m < 4; ++m) {
        int rowb = m0 + wr*64 + m*16 + lg*4;
        #pragma unroll
        for (int r = 0; r < 4; ++r) {
          int row = rowb + r;
          int b = row >> 11, s = row & 2047;
          C[((size_t)((b*NHEADS + h)*SEQ + s))*DK + dkk] = f2bf((acc[m][n][r] + bv) * scale);
        }
      }
    }
  }
}

// ---------------- flash attention, swapped-QK^T 32x32, single-buffer, 4 blocks/CU ----------------
// 4 waves x 32 q-rows = 128 q-rows/block. KVBLK=64. Occupancy is the overlap mechanism (m114):
// 16 waves/CU cross-cover the serialized staging phases.
__global__ __launch_bounds__(256, 4) void attn_kernel(const unsigned short* __restrict__ Q,
                                                      const unsigned short* __restrict__ K,
                                                      const unsigned short* __restrict__ V,
                                                      unsigned short* __restrict__ O) {
  __shared__ char lds[64*256 + 128*144];           // K 16KB + Vt 18KB (reused as O-bounce)
  unsigned short* Kl = (unsigned short*)lds;       // [64][128] bf16, XOR-swizzled rows
  unsigned short* Vt = (unsigned short*)(lds + 64*256); // [128 dv][72 kv] bf16 (padded)

  const int t  = threadIdx.x;
  const int l  = t & 63, w = t >> 6;
  const int q_ = l & 31, hi = l >> 5;
  const int bh = blockIdx.y;
  const int b  = bh >> 4, h = bh & 15;
  const int q0 = blockIdx.x * 128;

  const unsigned short* Qp = Q + (size_t)bh * SEQ * DK;
  const unsigned short* Kp = K + (size_t)bh * SEQ * DK;
  const unsigned short* Vp = V + (size_t)bh * SEQ * DK;

  // Q fragments for B-operand: lane holds Q[qrow][kk*16 + hi*8 .. +8]
  const int qrow = q0 + w*32 + q_;
  s16x8 aq[8];
  #pragma unroll
  for (int kk = 0; kk < 8; ++kk)
    aq[kk] = *(const s16x8*)(Qp + (size_t)qrow*DK + kk*16 + hi*8);

  f32x16 accO[4] = {};                 // C[dv][q = q_]
  float m = -INFINITY, L = 0.f;

  const int vp_ = t & 31;
  const int vd0 = (t >> 5) * 8;

  for (int kv0 = 0; kv0 < SEQ; kv0 += 64) {
    __syncthreads();
    // stage K: linear LDS dest, inverse-swizzled global source
    #pragma unroll
    for (int i = 0; i < 4; ++i) {
      int c   = t + 256*i;                 // 1024 chunks of 16B
      int row = c >> 4;
      int sb  = ((c & 15) << 4) ^ ((row & 15) << 4);
      async16((const char*)(Kp + (size_t)(kv0 + row)*DK) + sb, (char*)Kl + c*16);
    }
    // stage V transposed: Vt[dv][kv], kv pairs packed as b32
    #pragma unroll
    for (int rep = 0; rep < 2; ++rep) {
      int dvb = vd0 + rep*64;
      s16x8 va = *(const s16x8*)(Vp + (size_t)(kv0 + 2*vp_    )*DK + dvb);
      s16x8 vb = *(const s16x8*)(Vp + (size_t)(kv0 + 2*vp_ + 1)*DK + dvb);
      #pragma unroll
      for (int j = 0; j < 8; ++j) {
        unsigned int pk = (unsigned int)(unsigned short)va[j]
                        | ((unsigned int)(unsigned short)vb[j] << 16);
        *(unsigned int*)&Vt[(dvb + j)*72 + 2*vp_] = pk;
      }
    }
    asm volatile("s_waitcnt vmcnt(0) lgkmcnt(0)" ::: "memory");
    __syncthreads();

    // ---- S^T[kv][q] = K Q^T (log2-domain scores) ----
    f32x16 S0 = {}, S1 = {};
    #pragma unroll
    for (int t2 = 0; t2 < 2; ++t2) {
      int krow = t2*32 + q_;
      const char* kb = (const char*)Kl + krow*256;
      int swz = (krow & 15) << 4;
      #pragma unroll
      for (int kk = 0; kk < 8; ++kk) {
        s16x8 kf = *(const s16x8*)(kb + ((kk*32 + hi*16) ^ swz));
        if (t2 == 0) S0 = __builtin_amdgcn_mfma_f32_32x32x16_bf16(kf, aq[kk], S0, 0, 0, 0);
        else         S1 = __builtin_amdgcn_mfma_f32_32x32x16_bf16(kf, aq[kk], S1, 0, 0, 0);
      }
    }

    // ---- in-register online softmax (exp2 domain, defer-max THR=11 ~ e^7.6) ----
    f32x16 mx;
    #pragma unroll
    for (int r = 0; r < 16; ++r) mx[r] = fmaxf(S0[r], S1[r]);
    float m8_[8];
    #pragma unroll
    for (int r = 0; r < 8; ++r) m8_[r] = fmaxf(mx[r], mx[r+8]);
    float m4a = fmaxf(m8_[0], m8_[4]), m4b = fmaxf(m8_[1], m8_[5]);
    float m4c = fmaxf(m8_[2], m8_[6]), m4d = fmaxf(m8_[3], m8_[7]);
    float pmax = fmaxf(fmaxf(m4a, m4b), fmaxf(m4c, m4d));
    pmax = fmaxf(pmax, __shfl_xor(pmax, 32, 64));

    if (!__all(pmax <= m + 11.0f)) {
      float mnew = fmaxf(m, pmax);
      float corr = exp2f(m - mnew);
      m = mnew;
      L *= corr;
      #pragma unroll
      for (int sub = 0; sub < 4; ++sub)
        #pragma unroll
        for (int r = 0; r < 16; ++r) accO[sub][r] *= corr;
    }

    float rs0 = 0.f, rs1 = 0.f, rs2 = 0.f, rs3 = 0.f;
    #pragma unroll
    for (int r = 0; r < 4; ++r) {
      float a0 = exp2f(S0[r]    - m); S0[r]    = a0; rs0 += a0;
      float a1 = exp2f(S0[r+4]  - m); S0[r+4]  = a1; rs1 += a1;
      float a2 = exp2f(S0[r+8]  - m); S0[r+8]  = a2; rs2 += a2;
      float a3 = exp2f(S0[r+12] - m); S0[r+12] = a3; rs3 += a3;
      float b0 = exp2f(S1[r]    - m); S1[r]    = b0; rs0 += b0;
      float b1 = exp2f(S1[r+4]  - m); S1[r+4]  = b1; rs1 += b1;
      float b2 = exp2f(S1[r+8]  - m); S1[r+8]  = b2; rs2 += b2;
      float b3 = exp2f(S1[r+12] - m); S1[r+12] = b3; rs3 += b3;
    }
    float rs = (rs0 + rs1) + (rs2 + rs3);
    rs += __shfl_xor(rs, 32, 64);
    L += rs;

    // ---- P -> bf16 B-fragments via shfl_xor(32) + select ----
    s16x8 PB[4];
    #pragma unroll
    for (int t2 = 0; t2 < 2; ++t2) {
      #pragma unroll
      for (int half = 0; half < 2; ++half) {
        int bse = half*8;
        unsigned int pkA01, pkA23, pkB01, pkB23;
        if (t2 == 0) {
          pkA01 = packbf_c(S0[bse+0], S0[bse+1]);
          pkA23 = packbf_c(S0[bse+2], S0[bse+3]);
          pkB01 = packbf_c(S0[bse+4], S0[bse+5]);
          pkB23 = packbf_c(S0[bse+6], S0[bse+7]);
        } else {
          pkA01 = packbf_c(S1[bse+0], S1[bse+1]);
          pkA23 = packbf_c(S1[bse+2], S1[bse+3]);
          pkB01 = packbf_c(S1[bse+4], S1[bse+5]);
          pkB23 = packbf_c(S1[bse+6], S1[bse+7]);
        }
        unsigned int xA01 = __shfl_xor(pkA01, 32, 64);
        unsigned int xA23 = __shfl_xor(pkA23, 32, 64);
        unsigned int xB01 = __shfl_xor(pkB01, 32, 64);
        unsigned int xB23 = __shfl_xor(pkB23, 32, 64);
        union { unsigned int u[4]; s16x8 v; } f;
        f.u[0] = hi ? xB01 : pkA01;
        f.u[1] = hi ? xB23 : pkA23;
        f.u[2] = hi ? pkB01 : xA01;
        f.u[3] = hi ? pkB23 : xA23;
        PB[t2*2 + half] = f.v;
      }
    }

    // ---- O^T += V^T P^T : C[dv][q] ----
    #pragma unroll
    for (int sub = 0; sub < 4; ++sub) {
      const char* vb2 = (const char*)Vt + (size_t)(sub*32 + q_)*144 + hi*16;
      #pragma unroll
      for (int kk = 0; kk < 4; ++kk) {
        s16x8 vf = *(const s16x8*)(vb2 + kk*32);
        accO[sub] = __builtin_amdgcn_mfma_f32_32x32x16_bf16(vf, PB[kk], accO[sub], 0, 0, 0);
      }
    }
  }

  // ---- epilogue: per-wave LDS bounce to coalesce [q][dv] stores ----
  __syncthreads();   // all waves done with K/V before reuse
  unsigned short* Ob = (unsigned short*)lds + (size_t)w*4096;   // 8KB/wave
  float inv = 1.0f / L;
  #pragma unroll
  for (int sub = 0; sub < 4; ++sub)
    #pragma unroll
    for (int j = 0; j < 8; ++j) {
      unsigned int pw = packbf_c(accO[sub][2*j]*inv, accO[sub][2*j+1]*inv);
      int dv = sub*32 + (j&1)*2 + ((j>>1)*8) + 4*hi;
      *(unsigned int*)((char*)Ob + q_*256 + ((dv*2) ^ ((q_ & 15) << 4))) = pw;
    }
  asm volatile("s_waitcnt lgkmcnt(0)" ::: "memory");
  size_t gbase = ((size_t)(b*SEQ + q0 + w*32 + q_))*D_MODEL + h*DK;
  #pragma unroll
  for (int p = 0; p < 8; ++p) {
    int chunk = hi + 2*p;
    s16x8 ov = *(const s16x8*)((char*)Ob + q_*256 + ((chunk*16) ^ ((q_ & 15) << 4)));
    *(s16x8*)(O + gbase + chunk*8) = ov;
  }
}

extern "C" void kernel_launch(void* const* d_in, const int* in_sizes, int n_in,
                              void* d_out, int out_size, void* d_ws, size_t ws_size,
                              hipStream_t stream) {
  const float* q  = (const float*)d_in[0];
  const float* k  = (const float*)d_in[1];
  const float* v  = (const float*)d_in[2];
  const float* Wq = (const float*)d_in[3];
  const float* bq = (const float*)d_in[4];
  const float* Wk = (const float*)d_in[5];
  const float* bk = (const float*)d_in[6];
  const float* Wv = (const float*)d_in[7];
  const float* bv = (const float*)d_in[8];
  const float* Wo = (const float*)d_in[9];
  const float* bo = (const float*)d_in[10];
  float* out = (float*)d_out;

  char* ws = (char*)d_ws;
  const size_t SZT = (size_t)MROWS * D_MODEL * 2;
  const size_t SZW = (size_t)D_MODEL * D_MODEL * 2;

  unsigned short* qb  = (unsigned short*)(ws);
  unsigned short* kb  = (unsigned short*)(ws + SZT);
  unsigned short* vb  = (unsigned short*)(ws + 2*SZT);
  unsigned short* WqT = (unsigned short*)(ws + 3*SZT);
  unsigned short* WkT = (unsigned short*)(ws + 3*SZT + SZW);
  unsigned short* WvT = (unsigned short*)(ws + 3*SZT + 2*SZW);
  unsigned short* WoT = (unsigned short*)(ws + 3*SZT + 3*SZW);
  unsigned short* Qh  = (unsigned short*)(ws + 3*SZT + 4*SZW);
  unsigned short* Kh  = (unsigned short*)(ws + 4*SZT + 4*SZW);
  unsigned short* Vh  = (unsigned short*)(ws + 5*SZT + 4*SZW);
  unsigned short* Oc  = qb;   // qb dead after Q projection

  const int n8 = MROWS * D_MODEL / 8;
  f2b3_kernel<<<dim3(n8/256, 3), 256, 0, stream>>>(q, k, v, qb, kb, vb);
  wtrans_kernel<<<dim3(64, 64, 4), dim3(32, 8), 0, stream>>>(Wq, Wk, Wv, Wo, WqT, WkT, WvT, WoT);

  // 1/sqrt(128) * log2(e): scores computed directly in exp2 domain
  const float qscale = 0.1275174308f;
  gemm_bt<<<dim3(16, 32), 256, 0, stream>>>(qb, WqT, bq, Qh, MROWS, D_MODEL, D_MODEL, 1, qscale);
  gemm_bt<<<dim3(16, 32), 256, 0, stream>>>(kb, WkT, bk, Kh, MROWS, D_MODEL, D_MODEL, 1, 1.0f);
  gemm_bt<<<dim3(16, 32), 256, 0, stream>>>(vb, WvT, bv, Vh, MROWS, D_MODEL, D_MODEL, 1, 1.0f);

  attn_kernel<<<dim3(SEQ/128, BATCH*NHEADS), 256, 0, stream>>>(Qh, Kh, Vh, Oc);

  gemm_bt<<<dim3(16, 32), 256, 0, stream>>>(Oc, WoT, bo, out, MROWS, D_MODEL, D_MODEL, 0, 1.0f);
}

// Round 6
// 371.924 us; speedup vs baseline: 1.4026x; 1.4026x over previous
//
#include <hip/hip_runtime.h>
#include <hip/hip_bf16.h>
#include <stdint.h>

typedef float  f32x4  __attribute__((ext_vector_type(4)));
typedef float  f32x16 __attribute__((ext_vector_type(16)));
typedef short  s16x8  __attribute__((ext_vector_type(8)));

#define D_MODEL 2048
#define NHEADS  16
#define DK      128
#define BATCH   2
#define SEQ     2048
#define MROWS   (BATCH*SEQ)   // 4096

__device__ __forceinline__ unsigned short f2bf(float f) {
  union { float f; unsigned int u; } v; v.f = f;
  unsigned int r = v.u + 0x7FFFu + ((v.u >> 16) & 1u);
  return (unsigned short)(r >> 16);
}

// compiler-cast pack (m240: scalar casts fuse well; don't hand-write cvt_pk asm)
__device__ __forceinline__ unsigned int packbf_c(float lo, float hi) {
  __hip_bfloat16 l = __float2bfloat16(lo);
  __hip_bfloat16 h = __float2bfloat16(hi);
  unsigned short lu, hu;
  __builtin_memcpy(&lu, &l, 2);
  __builtin_memcpy(&hu, &h, 2);
  return (unsigned int)lu | ((unsigned int)hu << 16);
}

__device__ __forceinline__ void async16(const void* g, void* l) {
  __builtin_amdgcn_global_load_lds(
      (const __attribute__((address_space(1))) unsigned int*)g,
      (__attribute__((address_space(3))) unsigned int*)l,
      16, 0, 0);
}

// ---------------- fp32 -> bf16 convert, q/k/v in one launch ----------------
__global__ __launch_bounds__(256) void f2b3_kernel(const float* __restrict__ q,
                                                   const float* __restrict__ k,
                                                   const float* __restrict__ v,
                                                   unsigned short* __restrict__ qb,
                                                   unsigned short* __restrict__ kb,
                                                   unsigned short* __restrict__ vb) {
  const float* s; unsigned short* d;
  switch (blockIdx.y) {
    case 0:  s = q; d = qb; break;
    case 1:  s = k; d = kb; break;
    default: s = v; d = vb; break;
  }
  int i = blockIdx.x * 256 + threadIdx.x;
  const float4* s4 = (const float4*)s;
  float4 a = s4[2*i];
  float4 b = s4[2*i+1];
  s16x8 o;
  o[0] = (short)f2bf(a.x); o[1] = (short)f2bf(a.y);
  o[2] = (short)f2bf(a.z); o[3] = (short)f2bf(a.w);
  o[4] = (short)f2bf(b.x); o[5] = (short)f2bf(b.y);
  o[6] = (short)f2bf(b.z); o[7] = (short)f2bf(b.w);
  *(s16x8*)(d + 8*(size_t)i) = o;
}

// ---------------- weight transpose + convert: Wt[n][k] = bf16(W[k][n]) ----------------
__global__ __launch_bounds__(256) void wtrans_kernel(const float* __restrict__ Wq,
                                                     const float* __restrict__ Wk,
                                                     const float* __restrict__ Wv,
                                                     const float* __restrict__ Wo,
                                                     unsigned short* __restrict__ WqT,
                                                     unsigned short* __restrict__ WkT,
                                                     unsigned short* __restrict__ WvT,
                                                     unsigned short* __restrict__ WoT) {
  const float* W; unsigned short* Wt;
  switch (blockIdx.z) {
    case 0:  W = Wq; Wt = WqT; break;
    case 1:  W = Wk; Wt = WkT; break;
    case 2:  W = Wv; Wt = WvT; break;
    default: W = Wo; Wt = WoT; break;
  }
  __shared__ float tl[32][33];
  int x = threadIdx.x, y = threadIdx.y;
  int n0 = blockIdx.x * 32, k0 = blockIdx.y * 32;
  #pragma unroll
  for (int j = 0; j < 32; j += 8)
    tl[y + j][x] = W[(size_t)(k0 + y + j) * D_MODEL + n0 + x];
  __syncthreads();
  #pragma unroll
  for (int j = 0; j < 32; j += 8)
    Wt[(size_t)(n0 + y + j) * D_MODEL + k0 + x] = f2bf(tl[x][y + j]);
}

// ---------------- GEMM core, 2-phase counted-prefetch (T3-min) ----------------
// C[m][n] = sum_k A[m][k]*Bt[n][k]; epilogue per mode.
// mode 0: fp32 [M][N] out, +bias.  mode 1: bf16 head-split [B,H,S,dk], (acc+bias)*scale.
__device__ __forceinline__ void gemm_core(const unsigned short* __restrict__ A,
                                          const unsigned short* __restrict__ Bt,
                                          const float* __restrict__ bias,
                                          void* __restrict__ Cout,
                                          int M, int N, int K,
                                          int mode, float scale,
                                          int m0, int n0,
                                          unsigned short* As0, unsigned short* As1,
                                          unsigned short* Bs0, unsigned short* Bs1) {
  const int t  = threadIdx.x;
  const int l  = t & 63, w = t >> 6;
  const int wr = w >> 1, wc = w & 1;
  const int lr = l & 15, lg = l >> 4;

  unsigned short* Asb[2] = {As0, As1};
  unsigned short* Bsb[2] = {Bs0, Bs1};

  const int c0row = t >> 2, c0col = (t & 3) * 8;
  const int c1row = (t + 256) >> 2, c1col = ((t + 256) & 3) * 8;

  // prologue: stage k0=0 into buf 0
  async16(A  + (size_t)(m0 + c0row)*K + c0col, (char*)As0 + t*16);
  async16(Bt + (size_t)(n0 + c0row)*K + c0col, (char*)Bs0 + t*16);
  async16(A  + (size_t)(m0 + c1row)*K + c1col, (char*)As0 + (t+256)*16);
  async16(Bt + (size_t)(n0 + c1row)*K + c1col, (char*)Bs0 + (t+256)*16);
  asm volatile("s_waitcnt vmcnt(0)" ::: "memory");
  __syncthreads();

  f32x4 acc[4][4] = {};

  for (int k0 = 0; k0 < K; k0 += 32) {
    const int cur = (k0 >> 5) & 1;
    if (k0 + 32 < K) {
      const int kn = k0 + 32;
      async16(A  + (size_t)(m0 + c0row)*K + kn + c0col, (char*)Asb[cur^1] + t*16);
      async16(Bt + (size_t)(n0 + c0row)*K + kn + c0col, (char*)Bsb[cur^1] + t*16);
      async16(A  + (size_t)(m0 + c1row)*K + kn + c1col, (char*)Asb[cur^1] + (t+256)*16);
      async16(Bt + (size_t)(n0 + c1row)*K + kn + c1col, (char*)Bsb[cur^1] + (t+256)*16);
    }

    s16x8 af[4], bfr[4];
    #pragma unroll
    for (int m = 0; m < 4; ++m)
      af[m] = *(const s16x8*)&Asb[cur][(wr*64 + m*16 + lr)*32 + 8*lg];
    #pragma unroll
    for (int n = 0; n < 4; ++n)
      bfr[n] = *(const s16x8*)&Bsb[cur][(wc*64 + n*16 + lr)*32 + 8*lg];
    #pragma unroll
    for (int m = 0; m < 4; ++m)
      #pragma unroll
      for (int n = 0; n < 4; ++n)
        acc[m][n] = __builtin_amdgcn_mfma_f32_16x16x32_bf16(af[m], bfr[n], acc[m][n], 0, 0, 0);

    asm volatile("s_waitcnt vmcnt(0)" ::: "memory");   // next-tile loads landed
    __syncthreads();
  }

  if (mode == 0) {
    float* C = (float*)Cout;
    #pragma unroll
    for (int n = 0; n < 4; ++n) {
      int col = n0 + wc*64 + n*16 + lr;
      float bv = bias[col];
      #pragma unroll
      for (int m = 0; m < 4; ++m) {
        int rowb = m0 + wr*64 + m*16 + lg*4;
        #pragma unroll
        for (int r = 0; r < 4; ++r)
          C[(size_t)(rowb + r)*N + col] = (acc[m][n][r] + bv) * scale;
      }
    }
  } else {
    unsigned short* C = (unsigned short*)Cout;
    #pragma unroll
    for (int n = 0; n < 4; ++n) {
      int col = n0 + wc*64 + n*16 + lr;
      float bv = bias[col];
      int h = col >> 7, dkk = col & 127;
      #pragma unroll
      for (int m = 0; m < 4; ++m) {
        int rowb = m0 + wr*64 + m*16 + lg*4;
        #pragma unroll
        for (int r = 0; r < 4; ++r) {
          int row = rowb + r;
          int b = row >> 11, s = row & 2047;
          C[((size_t)((b*NHEADS + h)*SEQ + s))*DK + dkk] = f2bf((acc[m][n][r] + bv) * scale);
        }
      }
    }
  }
}

// out-projection GEMM (mode 0)
__global__ __launch_bounds__(256) void gemm_bt(const unsigned short* __restrict__ A,
                                               const unsigned short* __restrict__ Bt,
                                               const float* __restrict__ bias,
                                               void* __restrict__ Cout,
                                               int M, int N, int K,
                                               int mode, float scale) {
  __shared__ unsigned short As[2][128*32];
  __shared__ unsigned short Bs[2][128*32];
  gemm_core(A, Bt, bias, Cout, M, N, K, mode, scale,
            blockIdx.y*128, blockIdx.x*128, As[0], As[1], Bs[0], Bs[1]);
}

// fused Q/K/V projections: one launch, grid.z selects the projection.
__global__ __launch_bounds__(256) void gemm_qkv3(const unsigned short* __restrict__ qb,
                                                 const unsigned short* __restrict__ kb,
                                                 const unsigned short* __restrict__ vb,
                                                 const unsigned short* __restrict__ WT,   // [3][2048][2048] contiguous
                                                 const float* __restrict__ bq,
                                                 const float* __restrict__ bk,
                                                 const float* __restrict__ bv,
                                                 unsigned short* __restrict__ Hout,       // [3][B,H,S,dk] contiguous
                                                 float qscale) {
  __shared__ unsigned short As[2][128*32];
  __shared__ unsigned short Bs[2][128*32];
  const int z = blockIdx.z;
  const unsigned short* A = (z == 0) ? qb : (z == 1) ? kb : vb;
  const float* bias       = (z == 0) ? bq : (z == 1) ? bk : bv;
  const float scale       = (z == 0) ? qscale : 1.0f;
  const unsigned short* Bt = WT + (size_t)z * D_MODEL * D_MODEL;
  unsigned short* Cout     = Hout + (size_t)z * MROWS * D_MODEL;
  gemm_core(A, Bt, bias, Cout, MROWS, D_MODEL, D_MODEL, 1, scale,
            blockIdx.y*128, blockIdx.x*128, As[0], As[1], Bs[0], Bs[1]);
}

// ---------------- flash attention, swapped-QK^T 32x32, single-buffer ----------------
// 4 waves x 32 q-rows = 128 q-rows/block. KVBLK=64. Grid 512 blocks = 2/CU (grid-limited).
// (256,2): VGPR budget 256 -> compiler uses ~128, no spill (round-5 lesson: (256,4) forced
// VGPR=64 and 940MB of scratch traffic).
__global__ __launch_bounds__(256, 2) void attn_kernel(const unsigned short* __restrict__ Q,
                                                      const unsigned short* __restrict__ K,
                                                      const unsigned short* __restrict__ V,
                                                      unsigned short* __restrict__ O) {
  __shared__ char lds[64*256 + 128*144];           // K 16KB + Vt 18KB (reused as O-bounce)
  unsigned short* Kl = (unsigned short*)lds;       // [64][128] bf16, XOR-swizzled rows
  unsigned short* Vt = (unsigned short*)(lds + 64*256); // [128 dv][72 kv] bf16 (padded)

  const int t  = threadIdx.x;
  const int l  = t & 63, w = t >> 6;
  const int q_ = l & 31, hi = l >> 5;
  const int bh = blockIdx.y;
  const int b  = bh >> 4, h = bh & 15;
  const int q0 = blockIdx.x * 128;

  const unsigned short* Qp = Q + (size_t)bh * SEQ * DK;
  const unsigned short* Kp = K + (size_t)bh * SEQ * DK;
  const unsigned short* Vp = V + (size_t)bh * SEQ * DK;

  // Q fragments for B-operand: lane holds Q[qrow][kk*16 + hi*8 .. +8]
  const int qrow = q0 + w*32 + q_;
  s16x8 aq[8];
  #pragma unroll
  for (int kk = 0; kk < 8; ++kk)
    aq[kk] = *(const s16x8*)(Qp + (size_t)qrow*DK + kk*16 + hi*8);

  f32x16 accO[4] = {};                 // C[dv][q = q_]
  float m = -INFINITY, L = 0.f;

  const int vp_ = t & 31;
  const int vd0 = (t >> 5) * 8;

  for (int kv0 = 0; kv0 < SEQ; kv0 += 64) {
    __syncthreads();
    // stage K: linear LDS dest, inverse-swizzled global source
    #pragma unroll
    for (int i = 0; i < 4; ++i) {
      int c   = t + 256*i;                 // 1024 chunks of 16B
      int row = c >> 4;
      int sb  = ((c & 15) << 4) ^ ((row & 15) << 4);
      async16((const char*)(Kp + (size_t)(kv0 + row)*DK) + sb, (char*)Kl + c*16);
    }
    // stage V transposed: Vt[dv][kv], kv pairs packed as b32
    #pragma unroll
    for (int rep = 0; rep < 2; ++rep) {
      int dvb = vd0 + rep*64;
      s16x8 va = *(const s16x8*)(Vp + (size_t)(kv0 + 2*vp_    )*DK + dvb);
      s16x8 vb = *(const s16x8*)(Vp + (size_t)(kv0 + 2*vp_ + 1)*DK + dvb);
      #pragma unroll
      for (int j = 0; j < 8; ++j) {
        unsigned int pk = (unsigned int)(unsigned short)va[j]
                        | ((unsigned int)(unsigned short)vb[j] << 16);
        *(unsigned int*)&Vt[(dvb + j)*72 + 2*vp_] = pk;
      }
    }
    asm volatile("s_waitcnt vmcnt(0) lgkmcnt(0)" ::: "memory");
    __syncthreads();

    // ---- S^T[kv][q] = K Q^T (log2-domain scores) ----
    f32x16 S0 = {}, S1 = {};
    #pragma unroll
    for (int t2 = 0; t2 < 2; ++t2) {
      int krow = t2*32 + q_;
      const char* kb = (const char*)Kl + krow*256;
      int swz = (krow & 15) << 4;
      #pragma unroll
      for (int kk = 0; kk < 8; ++kk) {
        s16x8 kf = *(const s16x8*)(kb + ((kk*32 + hi*16) ^ swz));
        if (t2 == 0) S0 = __builtin_amdgcn_mfma_f32_32x32x16_bf16(kf, aq[kk], S0, 0, 0, 0);
        else         S1 = __builtin_amdgcn_mfma_f32_32x32x16_bf16(kf, aq[kk], S1, 0, 0, 0);
      }
    }

    // ---- in-register online softmax (exp2 domain, defer-max THR=11) ----
    f32x16 mx;
    #pragma unroll
    for (int r = 0; r < 16; ++r) mx[r] = fmaxf(S0[r], S1[r]);
    float m8_[8];
    #pragma unroll
    for (int r = 0; r < 8; ++r) m8_[r] = fmaxf(mx[r], mx[r+8]);
    float m4a = fmaxf(m8_[0], m8_[4]), m4b = fmaxf(m8_[1], m8_[5]);
    float m4c = fmaxf(m8_[2], m8_[6]), m4d = fmaxf(m8_[3], m8_[7]);
    float pmax = fmaxf(fmaxf(m4a, m4b), fmaxf(m4c, m4d));
    pmax = fmaxf(pmax, __shfl_xor(pmax, 32, 64));

    if (!__all(pmax <= m + 11.0f)) {
      float mnew = fmaxf(m, pmax);
      float corr = exp2f(m - mnew);
      m = mnew;
      L *= corr;
      #pragma unroll
      for (int sub = 0; sub < 4; ++sub)
        #pragma unroll
        for (int r = 0; r < 16; ++r) accO[sub][r] *= corr;
    }

    float rs0 = 0.f, rs1 = 0.f, rs2 = 0.f, rs3 = 0.f;
    #pragma unroll
    for (int r = 0; r < 4; ++r) {
      float a0 = exp2f(S0[r]    - m); S0[r]    = a0; rs0 += a0;
      float a1 = exp2f(S0[r+4]  - m); S0[r+4]  = a1; rs1 += a1;
      float a2 = exp2f(S0[r+8]  - m); S0[r+8]  = a2; rs2 += a2;
      float a3 = exp2f(S0[r+12] - m); S0[r+12] = a3; rs3 += a3;
      float b0 = exp2f(S1[r]    - m); S1[r]    = b0; rs0 += b0;
      float b1 = exp2f(S1[r+4]  - m); S1[r+4]  = b1; rs1 += b1;
      float b2 = exp2f(S1[r+8]  - m); S1[r+8]  = b2; rs2 += b2;
      float b3 = exp2f(S1[r+12] - m); S1[r+12] = b3; rs3 += b3;
    }
    float rs = (rs0 + rs1) + (rs2 + rs3);
    rs += __shfl_xor(rs, 32, 64);
    L += rs;

    // ---- P -> bf16 B-fragments via shfl_xor(32) + select ----
    s16x8 PB[4];
    #pragma unroll
    for (int t2 = 0; t2 < 2; ++t2) {
      #pragma unroll
      for (int half = 0; half < 2; ++half) {
        int bse = half*8;
        unsigned int pkA01, pkA23, pkB01, pkB23;
        if (t2 == 0) {
          pkA01 = packbf_c(S0[bse+0], S0[bse+1]);
          pkA23 = packbf_c(S0[bse+2], S0[bse+3]);
          pkB01 = packbf_c(S0[bse+4], S0[bse+5]);
          pkB23 = packbf_c(S0[bse+6], S0[bse+7]);
        } else {
          pkA01 = packbf_c(S1[bse+0], S1[bse+1]);
          pkA23 = packbf_c(S1[bse+2], S1[bse+3]);
          pkB01 = packbf_c(S1[bse+4], S1[bse+5]);
          pkB23 = packbf_c(S1[bse+6], S1[bse+7]);
        }
        unsigned int xA01 = __shfl_xor(pkA01, 32, 64);
        unsigned int xA23 = __shfl_xor(pkA23, 32, 64);
        unsigned int xB01 = __shfl_xor(pkB01, 32, 64);
        unsigned int xB23 = __shfl_xor(pkB23, 32, 64);
        union { unsigned int u[4]; s16x8 v; } f;
        f.u[0] = hi ? xB01 : pkA01;
        f.u[1] = hi ? xB23 : pkA23;
        f.u[2] = hi ? pkB01 : xA01;
        f.u[3] = hi ? pkB23 : xA23;
        PB[t2*2 + half] = f.v;
      }
    }

    // ---- O^T += V^T P^T : C[dv][q] ----
    #pragma unroll
    for (int sub = 0; sub < 4; ++sub) {
      const char* vb2 = (const char*)Vt + (size_t)(sub*32 + q_)*144 + hi*16;
      #pragma unroll
      for (int kk = 0; kk < 4; ++kk) {
        s16x8 vf = *(const s16x8*)(vb2 + kk*32);
        accO[sub] = __builtin_amdgcn_mfma_f32_32x32x16_bf16(vf, PB[kk], accO[sub], 0, 0, 0);
      }
    }
  }

  // ---- epilogue: per-wave LDS bounce to coalesce [q][dv] stores ----
  __syncthreads();   // all waves done with K/V before reuse
  unsigned short* Ob = (unsigned short*)lds + (size_t)w*4096;   // 8KB/wave
  float inv = 1.0f / L;
  #pragma unroll
  for (int sub = 0; sub < 4; ++sub)
    #pragma unroll
    for (int j = 0; j < 8; ++j) {
      unsigned int pw = packbf_c(accO[sub][2*j]*inv, accO[sub][2*j+1]*inv);
      int dv = sub*32 + (j&1)*2 + ((j>>1)*8) + 4*hi;
      *(unsigned int*)((char*)Ob + q_*256 + ((dv*2) ^ ((q_ & 15) << 4))) = pw;
    }
  asm volatile("s_waitcnt lgkmcnt(0)" ::: "memory");
  size_t gbase = ((size_t)(b*SEQ + q0 + w*32 + q_))*D_MODEL + h*DK;
  #pragma unroll
  for (int p = 0; p < 8; ++p) {
    int chunk = hi + 2*p;
    s16x8 ov = *(const s16x8*)((char*)Ob + q_*256 + ((chunk*16) ^ ((q_ & 15) << 4)));
    *(s16x8*)(O + gbase + chunk*8) = ov;
  }
}

extern "C" void kernel_launch(void* const* d_in, const int* in_sizes, int n_in,
                              void* d_out, int out_size, void* d_ws, size_t ws_size,
                              hipStream_t stream) {
  const float* q  = (const float*)d_in[0];
  const float* k  = (const float*)d_in[1];
  const float* v  = (const float*)d_in[2];
  const float* Wq = (const float*)d_in[3];
  const float* bq = (const float*)d_in[4];
  const float* Wk = (const float*)d_in[5];
  const float* bk = (const float*)d_in[6];
  const float* Wv = (const float*)d_in[7];
  const float* bv = (const float*)d_in[8];
  const float* Wo = (const float*)d_in[9];
  const float* bo = (const float*)d_in[10];
  float* out = (float*)d_out;

  char* ws = (char*)d_ws;
  const size_t SZT = (size_t)MROWS * D_MODEL * 2;
  const size_t SZW = (size_t)D_MODEL * D_MODEL * 2;

  unsigned short* qb  = (unsigned short*)(ws);
  unsigned short* kb  = (unsigned short*)(ws + SZT);
  unsigned short* vb  = (unsigned short*)(ws + 2*SZT);
  unsigned short* WqT = (unsigned short*)(ws + 3*SZT);            // [3][2048][2048] contiguous
  unsigned short* WkT = (unsigned short*)(ws + 3*SZT + SZW);
  unsigned short* WvT = (unsigned short*)(ws + 3*SZT + 2*SZW);
  unsigned short* WoT = (unsigned short*)(ws + 3*SZT + 3*SZW);
  unsigned short* Qh  = (unsigned short*)(ws + 3*SZT + 4*SZW);    // [3][B,H,S,dk] contiguous
  unsigned short* Kh  = (unsigned short*)(ws + 4*SZT + 4*SZW);
  unsigned short* Vh  = (unsigned short*)(ws + 5*SZT + 4*SZW);
  unsigned short* Oc  = qb;   // qb dead after Q projection

  const int n8 = MROWS * D_MODEL / 8;
  f2b3_kernel<<<dim3(n8/256, 3), 256, 0, stream>>>(q, k, v, qb, kb, vb);
  wtrans_kernel<<<dim3(64, 64, 4), dim3(32, 8), 0, stream>>>(Wq, Wk, Wv, Wo, WqT, WkT, WvT, WoT);

  // 1/sqrt(128) * log2(e): scores computed directly in exp2 domain
  const float qscale = 0.1275174308f;
  gemm_qkv3<<<dim3(16, 32, 3), 256, 0, stream>>>(qb, kb, vb, WqT, bq, bk, bv, Qh, qscale);

  attn_kernel<<<dim3(SEQ/128, BATCH*NHEADS), 256, 0, stream>>>(Qh, Kh, Vh, Oc);

  gemm_bt<<<dim3(16, 32), 256, 0, stream>>>(Oc, WoT, bo, out, MROWS, D_MODEL, D_MODEL, 0, 1.0f);
}